// Round 5
// baseline (360.311 us; speedup 1.0000x reference)
//
#include <hip/hip_runtime.h>
#include <math.h>

// ---------------------------------------------------------------------------
// GATRegressor: 2x GATConv(128->128, heads=1, self-loops) + max/mean pool + FC
// N=50000 nodes, E=1.6M edges, G=512 graphs.
// R20: aggregate Phase B rewrite. Aggregate is now 2x ~113us = 64% of total;
// gather of (E+N)*256B=422MB/layer runs at only 3.7 TB/s effective (L3-
// resident, latency/MLP-bound, VALU ~5%). New layout: quarter-wave (16 lanes
// x ushort8 = 16B/lane, the coalescing sweet spot) per row, 8 loads/lane per
// batch => 32 rows & 128B/lane in flight (was 16 rows, 64B/lane); typical
// D~33 node: 2 iters/16 loads (was 3/24). acc aa[4][8] static-indexed, 4
// independent FMA chains; cross-qw reduce via shfl_xor 16/32.
// gemmscat (split-bf16 MFMA + fused scatter, R19) / poolfc frozen.
// ---------------------------------------------------------------------------

#define LEAKY 0.2f
#define CAP 128           // col slots per node (P(deg>127) ~ 0 at Poisson(32))
#define CSTRIDE 16        // cnt padding: 1 counter per 64B line

typedef short bf16x8 __attribute__((ext_vector_type(8)));
typedef float f32x4 __attribute__((ext_vector_type(4)));
typedef unsigned short ushort8 __attribute__((ext_vector_type(8)));

__device__ __forceinline__ unsigned short f2bf(float x) {
    unsigned int u = __float_as_uint(x);
    unsigned int r = (u + 0x7FFFu + ((u >> 16) & 1u)) >> 16;   // RN-even
    return (unsigned short)r;
}
__device__ __forceinline__ float bf2f(unsigned short b) {
    return __uint_as_float((unsigned int)b << 16);
}

// Fat kernel. Blocks [0, gemmBlocks): hb[n x 128] = bf16(act(A) @ W) + fused
// asv/adv row-dots (split-bf16 MFMA, fp32-accurate). Blocks [gemmBlocks,...):
// XCD-partitioned edge scatter (g = blockIdx&7; locality heuristic only).
__global__ __launch_bounds__(256, 5) void gemmscat(
        const float* __restrict__ A,             // fp32 A rows
        const float* __restrict__ W,
        unsigned short* __restrict__ Cb,
        const float* __restrict__ a_src,
        const float* __restrict__ a_dst,
        float* __restrict__ asv,
        float* __restrict__ adv,
        int n, int applyRelu, int gemmBlocks,
        const int* __restrict__ ei,
        int* __restrict__ cnt,
        unsigned short* __restrict__ col,
        int E) {
    // Bt[0]=W-hi half, Bt[1]=W-lo half: [64 cols][128 k] bf16, swizzled.
    // Bt[0] reused as Cst[64][128] ushort for the coalesced hb write-out.
    __shared__ __align__(16) unsigned short Bt[2][64 * 128];

    if ((int)blockIdx.x >= gemmBlocks) {
        // ---------------- scatter path (1 chunk of 4096 edges / 8 blocks) ---
        const int b = (int)blockIdx.x - gemmBlocks;
        const int g = (int)blockIdx.x & 7;               // raw idx -> XCD id
        const int lo = (int)(((long long)n * g) >> 3);
        const int hi = (int)(((long long)n * (g + 1)) >> 3);
        const int base = (b >> 3) * 4096;
        int4 dv[4], sv[4];
        int ok[4];
#pragma unroll
        for (int t = 0; t < 4; ++t) {
            int i0 = base + t * 1024 + (int)threadIdx.x * 4;
            ok[t] = (i0 < E);        // chunk boundaries and E are %4 == 0
            if (ok[t]) {
                dv[t] = *(const int4*)(ei + (size_t)E + i0);   // dst row
                sv[t] = *(const int4*)(ei + i0);               // src row
            }
        }
#pragma unroll
        for (int t = 0; t < 4; ++t) {
            if (!ok[t]) continue;
            int dd[4] = { dv[t].x, dv[t].y, dv[t].z, dv[t].w };
            int ss[4] = { sv[t].x, sv[t].y, sv[t].z, sv[t].w };
#pragma unroll
            for (int j = 0; j < 4; ++j) {
                int d = dd[j];
                if (d >= lo && d < hi) {
                    int pos = atomicAdd(&cnt[(size_t)d * CSTRIDE], 1);
                    if (pos < CAP) col[(size_t)d * CAP + pos] = (unsigned short)ss[j];
                }
            }
        }
        return;
    }

    // ---------------- MFMA gemm path ----------------------------------------
    const int tid = threadIdx.x;
    const int wv = tid >> 6;          // wave 0..3 -> rows wv*16..+15
    const int lane = tid & 63;
    const int cl = lane & 15;         // col-in-tile / row-in-tile
    const int kg = lane >> 4;         // k group 0..3

    // ---- A fragments hi/lo: row = row0 + wv*16 + cl, k = ks*32 + kg*8 + j --
    const int row0 = blockIdx.x * 64;
    const int row = row0 + wv * 16 + cl;
    bf16x8 ahi[4], alo[4];
#pragma unroll
    for (int ks = 0; ks < 4; ++ks) {
        int k0 = ks * 32 + kg * 8;
        float vv[8] = {0.f, 0.f, 0.f, 0.f, 0.f, 0.f, 0.f, 0.f};
        if (row < n) {
            float4 v0 = *(const float4*)(A + (size_t)row * 128 + k0);
            float4 v1 = *(const float4*)(A + (size_t)row * 128 + k0 + 4);
            vv[0] = v0.x; vv[1] = v0.y; vv[2] = v0.z; vv[3] = v0.w;
            vv[4] = v1.x; vv[5] = v1.y; vv[6] = v1.z; vv[7] = v1.w;
            if (applyRelu) {
#pragma unroll
                for (int u = 0; u < 8; ++u) vv[u] = fmaxf(vv[u], 0.f);
            }
        }
#pragma unroll
        for (int u = 0; u < 8; ++u) {
            unsigned short h = f2bf(vv[u]);
            ahi[ks][u] = (short)h;
            alo[ks][u] = (short)f2bf(vv[u] - bf2f(h));
        }
    }

    f32x4 acc[8];
#pragma unroll
    for (int ci = 0; ci < 8; ++ci) {
        acc[ci][0] = 0.f; acc[ci][1] = 0.f; acc[ci][2] = 0.f; acc[ci][3] = 0.f;
    }

    // ---- two column halves: stage W hi/lo -> LDS, then MFMA ---------------
#pragma unroll
    for (int h = 0; h < 2; ++h) {
        __syncthreads();   // prev half's reads done / Bt safe to overwrite
        {
            int c64 = tid & 63;            // col within half
            int c = h * 64 + c64;
            int kh = tid >> 6;             // 0..3
#pragma unroll
            for (int j = 0; j < 4; ++j) {
                int kb = kh * 32 + j * 8;
                unsigned short thi[8], tlo[8];
#pragma unroll
                for (int u = 0; u < 8; ++u) {
                    float v = W[(size_t)(kb + u) * 128 + c];  // coalesced/wave
                    unsigned short hh = f2bf(v);
                    thi[u] = hh;
                    tlo[u] = f2bf(v - bf2f(hh));
                }
                int byteoff = (c64 * 256 + kb * 2) ^ ((c64 & 7) << 4);
                *(uint4*)((char*)Bt[0] + byteoff) = *(const uint4*)thi;
                *(uint4*)((char*)Bt[1] + byteoff) = *(const uint4*)tlo;
            }
        }
        __syncthreads();   // Bt ready
#pragma unroll
        for (int ks = 0; ks < 4; ++ks) {
            int k0 = ks * 32 + kg * 8;
#pragma unroll
            for (int ct = 0; ct < 4; ++ct) {
                int c64 = ct * 16 + cl;
                int byteoff = (c64 * 256 + k0 * 2) ^ ((c64 & 7) << 4);
                bf16x8 bhi = *(const bf16x8*)((const char*)Bt[0] + byteoff);
                bf16x8 blo = *(const bf16x8*)((const char*)Bt[1] + byteoff);
                int ci = h * 4 + ct;       // global col tile: c = ci*16 + cl
                acc[ci] = __builtin_amdgcn_mfma_f32_16x16x32_bf16(
                    ahi[ks], bhi, acc[ci], 0, 0, 0);
                acc[ci] = __builtin_amdgcn_mfma_f32_16x16x32_bf16(
                    ahi[ks], blo, acc[ci], 0, 0, 0);
                acc[ci] = __builtin_amdgcn_mfma_f32_16x16x32_bf16(
                    alo[ks], bhi, acc[ci], 0, 0, 0);
            }
        }
    }

    // ---- epilogue 1: asv/adv row dots via in-register shuffle reduce ----
    // C/D layout: col = ci*16 + cl, row(within wave tile) = kg*4 + r.
    {
        float ps[4] = {0.f, 0.f, 0.f, 0.f};
        float pd[4] = {0.f, 0.f, 0.f, 0.f};
#pragma unroll
        for (int ci = 0; ci < 8; ++ci) {
            float as_ = a_src[ci * 16 + cl];
            float ad_ = a_dst[ci * 16 + cl];
#pragma unroll
            for (int r = 0; r < 4; ++r) {
                ps[r] += acc[ci][r] * as_;
                pd[r] += acc[ci][r] * ad_;
            }
        }
#pragma unroll
        for (int r = 0; r < 4; ++r) {
#pragma unroll
            for (int off = 1; off < 16; off <<= 1) {
                ps[r] += __shfl_xor(ps[r], off, 64);
                pd[r] += __shfl_xor(pd[r], off, 64);
            }
        }
        if (cl == 0) {
#pragma unroll
            for (int r = 0; r < 4; ++r) {
                int rr = row0 + wv * 16 + kg * 4 + r;
                if (rr < n) { asv[rr] = ps[r]; adv[rr] = pd[r]; }
            }
        }
    }

    // ---- epilogue 2: hb bf16 via LDS transpose (reuse Bt[0] as Cst) ----
    __syncthreads();   // all waves done reading Bt
    unsigned short* Cst = Bt[0];       // [64][128] ushort = 16KB
#pragma unroll
    for (int ci = 0; ci < 8; ++ci) {
#pragma unroll
        for (int r = 0; r < 4; ++r)
            Cst[(wv * 16 + kg * 4 + r) * 128 + ci * 16 + cl] = f2bf(acc[ci][r]);
    }
    __syncthreads();
    {
        int r = tid >> 2, cb = (tid & 3) * 32;   // 64B per thread
        int grow = row0 + r;
        if (grow < n) {
            uint4* dst = (uint4*)(Cb + (size_t)grow * 128 + cb);
            const uint4* src = (const uint4*)(Cst + r * 128 + cb);
            dst[0] = src[0]; dst[1] = src[1]; dst[2] = src[2]; dst[3] = src[3];
        }
    }
}

// one wave per dst node: segment softmax + weighted feature sum.
// Phase A fp32 (asv/adv); virtual self-loop at entry deg (c=w).
// Phase B (R20): quarter-wave gather - 16 lanes x ushort8 (16B) per row,
// 8 loads/lane per batch = 32 rows & 128B/lane in flight; fp32 acc.
__global__ __launch_bounds__(256) void aggregate(const unsigned short* __restrict__ hb,
                                                 const int* __restrict__ cnt,
                                                 const unsigned short* __restrict__ col,
                                                 const float* __restrict__ asv,
                                                 const float* __restrict__ adv,
                                                 const float* __restrict__ bias,
                                                 float* __restrict__ out, int n) {
    __shared__ int   scol[4][128];
    __shared__ float swt[4][128];
    const int wv = threadIdx.x >> 6;
    const int lane = threadIdx.x & 63;
    const int w = blockIdx.x * 4 + wv;
    if (w >= n) return;
    int deg = cnt[(size_t)w * CSTRIDE];
    if (deg > CAP - 1) deg = CAP - 1;   // keep D <= 128 (statistically impossible)
    const int D = deg + 1;              // + virtual self-loop at entry deg
    const size_t start = (size_t)w * CAP;
    const float ad = adv[w];

    // ---- phase A: logits, wave max, exp-sum; stash (col, wgt) in LDS ----
    int c0 = 0, c1 = 0;
    float l0 = -INFINITY, l1 = -INFINITY;
    if (lane < D) {
        c0 = (lane < deg) ? (int)col[start + lane] : w;
        l0 = asv[c0] + ad;
        l0 = l0 > 0.f ? l0 : LEAKY * l0;
    }
    if (64 + lane < D) {
        c1 = (64 + lane < deg) ? (int)col[start + 64 + lane] : w;
        l1 = asv[c1] + ad;
        l1 = l1 > 0.f ? l1 : LEAKY * l1;
    }
    float m = fmaxf(l0, l1);
#pragma unroll
    for (int off = 32; off; off >>= 1) m = fmaxf(m, __shfl_xor(m, off, 64));
    float e0 = (lane < D) ? __expf(l0 - m) : 0.f;
    float e1 = (64 + lane < D) ? __expf(l1 - m) : 0.f;
    float s = e0 + e1;
#pragma unroll
    for (int off = 32; off; off >>= 1) s += __shfl_xor(s, off, 64);
    float inv = 1.f / s;
    if (lane < D)      { scol[wv][lane] = c0;      swt[wv][lane] = e0; }
    if (64 + lane < D) { scol[wv][64 + lane] = c1; swt[wv][64 + lane] = e1; }
    // wave-synchronous LDS producer/consumer: no barrier needed

    // ---- phase B: quarter-wave gather, 32 rows per batch ----
    const int qw = lane >> 4;        // quarter-wave 0..3
    const int sl = lane & 15;        // feature group [8sl..8sl+8)
    float aa[4][8];
#pragma unroll
    for (int q = 0; q < 4; ++q)
#pragma unroll
        for (int u = 0; u < 8; ++u) aa[q][u] = 0.f;

    for (int i = 0; i < D; i += 32) {
        int cs[8]; float ws[8];
#pragma unroll
        for (int j = 0; j < 8; ++j) {
            int idx = i + 4 * j + qw;
            int cc = idx < D ? idx : D - 1;       // clamp: load valid row
            cs[j] = scol[wv][cc];
            ws[j] = (idx < D) ? swt[wv][idx] : 0.f;   // mask via zero wgt
        }
        ushort8 rs[8];
#pragma unroll
        for (int j = 0; j < 8; ++j)
            rs[j] = *((const ushort8*)(hb + (size_t)cs[j] * 128) + sl);
#pragma unroll
        for (int j = 0; j < 8; ++j) {
#pragma unroll
            for (int u = 0; u < 8; ++u)
                aa[j & 3][u] += ws[j] * bf2f(rs[j][u]);
        }
    }
    // combine the 4 chains
#pragma unroll
    for (int u = 0; u < 8; ++u)
        aa[0][u] = (aa[0][u] + aa[1][u]) + (aa[2][u] + aa[3][u]);
    // cross-quarter-wave combine: lanes with equal sl hold same features
#pragma unroll
    for (int u = 0; u < 8; ++u) {
        aa[0][u] += __shfl_xor(aa[0][u], 16, 64);
        aa[0][u] += __shfl_xor(aa[0][u], 32, 64);
    }
    if (qw == 0) {
        float4 b0 = ((const float4*)bias)[sl * 2];
        float4 b1 = ((const float4*)bias)[sl * 2 + 1];
        float4 o0, o1;
        o0.x = fmaxf(aa[0][0] * inv + b0.x, 0.f);
        o0.y = fmaxf(aa[0][1] * inv + b0.y, 0.f);
        o0.z = fmaxf(aa[0][2] * inv + b0.z, 0.f);
        o0.w = fmaxf(aa[0][3] * inv + b0.w, 0.f);
        o1.x = fmaxf(aa[0][4] * inv + b1.x, 0.f);
        o1.y = fmaxf(aa[0][5] * inv + b1.y, 0.f);
        o1.z = fmaxf(aa[0][6] * inv + b1.z, 0.f);
        o1.w = fmaxf(aa[0][7] * inv + b1.w, 0.f);
        float4* op = (float4*)(out + (size_t)w * 128 + sl * 8);
        op[0] = o0; op[1] = o1;
    }
}

// one block (128 threads) per graph: max/mean pool + fc dot. Graph node range
// by binary search on sorted batch (R13-proven).
__global__ __launch_bounds__(128) void poolfc(const float* __restrict__ h2,
                                              const int* __restrict__ batch,
                                              const float* __restrict__ fcw,
                                              const float* __restrict__ fcb,
                                              float* __restrict__ out, int G, int n) {
    __shared__ int seg[2];
    int g = blockIdx.x;
    int f = threadIdx.x;
    if (f < 2) {
        int target = g + f;          // first idx with batch[idx] >= target
        int lo = 0, hi = n;
        while (lo < hi) {
            int mid = (lo + hi) >> 1;
            if (batch[mid] < target) lo = mid + 1; else hi = mid;
        }
        seg[f] = lo;
    }
    __syncthreads();
    int s = seg[0], e = seg[1];
    float m = -INFINITY, sum = 0.f;
    for (int node = s; node < e; ++node) {
        float v = h2[(size_t)node * 128 + f];
        m = fmaxf(m, v);
        sum += v;
    }
    int cnt = e - s;
    float maxp = (cnt > 0) ? m : 0.f;
    float cden = (float)(cnt > 0 ? cnt : 1);
    float meanp = sum / cden;
    float p = maxp * fcw[f] + meanp * fcw[128 + f];
    __shared__ float red[128];
    red[f] = p;
    __syncthreads();
    for (int off = 64; off; off >>= 1) {
        if (f < off) red[f] += red[f + off];
        __syncthreads();
    }
    if (f == 0) out[g] = red[0] + fcb[0];
}

extern "C" void kernel_launch(void* const* d_in, const int* in_sizes, int n_in,
                              void* d_out, int out_size, void* d_ws, size_t ws_size,
                              hipStream_t stream) {
    const int N = in_sizes[0] / 128;
    const int E = in_sizes[1] / 2;
    const int G = out_size;

    const float* x      = (const float*)d_in[0];
    const int*   ei     = (const int*)d_in[1];
    const int*   batch  = (const int*)d_in[2];
    const float* W1     = (const float*)d_in[3];
    const float* a_src1 = (const float*)d_in[4];
    const float* a_dst1 = (const float*)d_in[5];
    const float* b1     = (const float*)d_in[6];
    const float* W2     = (const float*)d_in[7];
    const float* a_src2 = (const float*)d_in[8];
    const float* a_dst2 = (const float*)d_in[9];
    const float* b2     = (const float*)d_in[10];
    const float* fcw    = (const float*)d_in[11];
    const float* fcb    = (const float*)d_in[12];
    float* out = (float*)d_out;

    // workspace carve (256B aligned).
    char* wp = (char*)d_ws;
    auto alloc = [&](size_t bytes) -> void* {
        void* p = (void*)wp;
        wp += (bytes + 255) & ~(size_t)255;
        return p;
    };
    int* cnt     = (int*)alloc(sizeof(int) * (size_t)N * CSTRIDE);
    unsigned short* col = (unsigned short*)alloc(sizeof(unsigned short) * (size_t)N * CAP);
    float* ha    = (float*)alloc(sizeof(float) * (size_t)N * 128);
    unsigned short* hb = (unsigned short*)alloc(sizeof(unsigned short) * (size_t)N * 128);
    float* asv   = (float*)alloc(sizeof(float) * N);
    float* adv   = (float*)alloc(sizeof(float) * N);

    hipMemsetAsync(cnt, 0, sizeof(int) * (size_t)N * CSTRIDE, stream);

    const int gemmGrid = (N + 63) / 64;
    const int waveGrid = (N + 3) / 4;      // 4 waves per 256-thread block
    const int scatGrid = ((E + 4095) / 4096) * 8;

    // layer 1 (input = relu(x)) fused with edge scatter.
    gemmscat<<<gemmGrid + scatGrid, 256, 0, stream>>>(
        x, W1, hb, a_src1, a_dst1, asv, adv, N, 1, gemmGrid, ei, cnt, col, E);
    aggregate<<<waveGrid, 256, 0, stream>>>(hb, cnt, col, asv, adv, b1, ha, N);

    // layer 2: fp32 ha input (relu already applied by aggregate); no scatter.
    gemmscat<<<gemmGrid, 256, 0, stream>>>(
        ha, W2, hb, a_src2, a_dst2, asv, adv, N, 0, gemmGrid, ei, cnt, col, E);
    aggregate<<<waveGrid, 256, 0, stream>>>(hb, cnt, col, asv, adv, b2, ha, N);

    // pooling + fc
    poolfc<<<G, 128, 0, stream>>>(ha, batch, fcw, fcb, out, G, N);
}

// Round 6
// 319.014 us; speedup vs baseline: 1.1295x; 1.1295x over previous
//
#include <hip/hip_runtime.h>
#include <math.h>

// ---------------------------------------------------------------------------
// GATRegressor: 2x GATConv(128->128, heads=1, self-loops) + max/mean pool + FC
// N=50000 nodes, E=1.6M edges, G=512 graphs.
// R21: scatter redesign. Evidence (R15-R20): 1.6M slot-allocating global
// atomicAdds run at a hard ~21G/s ceiling regardless of occupancy/MLP/padding
// => device-atomic throughput wall. Replace with two-phase LDS binning:
//  Phase A (fused into gemm-L1 grid): per 4096-edge block, rank edges into
//    dst-bins (d>>9, 512 dsts/bin) via LDS atomics; ONE global atomic per
//    (block,bin) [38K total vs 1.6M]; write packed (d<<16|s) 4B records to
//    contiguous per-bin windows.
//  Phase B (binbuild): one 512-thread block per bin; LDS-rank its ~16K edges
//    into col slots; write cnt[d] for all dsts (deletes the 3.2MB memset;
//    col writes are block-contiguous => L2-local, preserving R12 locality).
// Aggregate reverted to R19 half-wave form (R20 quarter-wave regressed).
// gemm (split-bf16 MFMA, R19) / poolfc frozen.
// ---------------------------------------------------------------------------

#define LEAKY 0.2f
#define CAP 128           // col slots per node (P(deg>127) ~ 0 at Poisson(32))
#define CAPB 20480        // records per bin (mean 16.4K, sd ~128)

typedef short bf16x8 __attribute__((ext_vector_type(8)));
typedef float f32x4 __attribute__((ext_vector_type(4)));

__device__ __forceinline__ unsigned short f2bf(float x) {
    unsigned int u = __float_as_uint(x);
    unsigned int r = (u + 0x7FFFu + ((u >> 16) & 1u)) >> 16;   // RN-even
    return (unsigned short)r;
}
__device__ __forceinline__ float bf2f(unsigned short b) {
    return __uint_as_float((unsigned int)b << 16);
}

// Fat kernel. Blocks [0, gemmBlocks): hb[n x 128] = bf16(act(A) @ W) + fused
// asv/adv row-dots (split-bf16 MFMA, fp32-accurate). Blocks [gemmBlocks,...):
// phase-A edge binning (4096 edges/block).
__global__ __launch_bounds__(256, 5) void gemmscat(
        const float* __restrict__ A,             // fp32 A rows
        const float* __restrict__ W,
        unsigned short* __restrict__ Cb,
        const float* __restrict__ a_src,
        const float* __restrict__ a_dst,
        float* __restrict__ asv,
        float* __restrict__ adv,
        int n, int applyRelu, int gemmBlocks,
        const int* __restrict__ ei,
        int* __restrict__ binCnt,
        unsigned* __restrict__ binBuf,
        int E) {
    // Bt[0]=W-hi half, Bt[1]=W-lo half: [64 cols][128 k] bf16, swizzled.
    // Bt[0] reused as Cst[64][128] ushort for hb write-out; phase-A blocks
    // alias the front of Bt as lcnt[128]/gbase[128].
    __shared__ __align__(16) unsigned short Bt[2][64 * 128];

    if ((int)blockIdx.x >= gemmBlocks) {
        // ---------------- phase A: bin 4096 edges (d>>9) --------------------
        int* lcnt  = (int*)Bt;          // [128]
        int* gbase = ((int*)Bt) + 128;  // [128]
        const int bb = (int)blockIdx.x - gemmBlocks;
        const int base = bb * 4096;
        const int tid = threadIdx.x;
        const int nbins = (n + 511) >> 9;
        if (tid < nbins) lcnt[tid] = 0;
        __syncthreads();

        int4 dv[4], sv[4];
        int ok[4];
#pragma unroll
        for (int t = 0; t < 4; ++t) {
            int i0 = base + t * 1024 + tid * 4;
            ok[t] = (i0 < E);        // chunk boundaries and E are %4 == 0
            if (ok[t]) {
                dv[t] = *(const int4*)(ei + (size_t)E + i0);   // dst row
                sv[t] = *(const int4*)(ei + i0);               // src row
            }
        }
        int rr[16];
        unsigned pk[16];
#pragma unroll
        for (int t = 0; t < 4; ++t) {
            int dd[4] = { dv[t].x, dv[t].y, dv[t].z, dv[t].w };
            int ss[4] = { sv[t].x, sv[t].y, sv[t].z, sv[t].w };
#pragma unroll
            for (int q = 0; q < 4; ++q) {
                int j = t * 4 + q;
                rr[j] = -1;
                if (ok[t]) {
                    unsigned d = (unsigned)dd[q];
                    pk[j] = (d << 16) | (unsigned)ss[q];
                    rr[j] = atomicAdd(&lcnt[d >> 9], 1);
                }
            }
        }
        __syncthreads();
        if (tid < nbins)
            gbase[tid] = (lcnt[tid] > 0) ? atomicAdd(&binCnt[tid], lcnt[tid]) : 0;
        __syncthreads();
#pragma unroll
        for (int j = 0; j < 16; ++j) {
            if (rr[j] >= 0) {
                int b = (int)(pk[j] >> 25);           // (d>>16)>>9
                int pos = gbase[b] + rr[j];
                if (pos < CAPB) binBuf[(size_t)b * CAPB + pos] = pk[j];
            }
        }
        return;
    }

    // ---------------- MFMA gemm path (frozen from R19) ----------------------
    const int tid = threadIdx.x;
    const int wv = tid >> 6;          // wave 0..3 -> rows wv*16..+15
    const int lane = tid & 63;
    const int cl = lane & 15;         // col-in-tile / row-in-tile
    const int kg = lane >> 4;         // k group 0..3

    // ---- A fragments hi/lo: row = row0 + wv*16 + cl, k = ks*32 + kg*8 + j --
    const int row0 = blockIdx.x * 64;
    const int row = row0 + wv * 16 + cl;
    bf16x8 ahi[4], alo[4];
#pragma unroll
    for (int ks = 0; ks < 4; ++ks) {
        int k0 = ks * 32 + kg * 8;
        float vv[8] = {0.f, 0.f, 0.f, 0.f, 0.f, 0.f, 0.f, 0.f};
        if (row < n) {
            float4 v0 = *(const float4*)(A + (size_t)row * 128 + k0);
            float4 v1 = *(const float4*)(A + (size_t)row * 128 + k0 + 4);
            vv[0] = v0.x; vv[1] = v0.y; vv[2] = v0.z; vv[3] = v0.w;
            vv[4] = v1.x; vv[5] = v1.y; vv[6] = v1.z; vv[7] = v1.w;
            if (applyRelu) {
#pragma unroll
                for (int u = 0; u < 8; ++u) vv[u] = fmaxf(vv[u], 0.f);
            }
        }
#pragma unroll
        for (int u = 0; u < 8; ++u) {
            unsigned short h = f2bf(vv[u]);
            ahi[ks][u] = (short)h;
            alo[ks][u] = (short)f2bf(vv[u] - bf2f(h));
        }
    }

    f32x4 acc[8];
#pragma unroll
    for (int ci = 0; ci < 8; ++ci) {
        acc[ci][0] = 0.f; acc[ci][1] = 0.f; acc[ci][2] = 0.f; acc[ci][3] = 0.f;
    }

    // ---- two column halves: stage W hi/lo -> LDS, then MFMA ---------------
#pragma unroll
    for (int h = 0; h < 2; ++h) {
        __syncthreads();   // prev half's reads done / Bt safe to overwrite
        {
            int c64 = tid & 63;            // col within half
            int c = h * 64 + c64;
            int kh = tid >> 6;             // 0..3
#pragma unroll
            for (int j = 0; j < 4; ++j) {
                int kb = kh * 32 + j * 8;
                unsigned short thi[8], tlo[8];
#pragma unroll
                for (int u = 0; u < 8; ++u) {
                    float v = W[(size_t)(kb + u) * 128 + c];  // coalesced/wave
                    unsigned short hh = f2bf(v);
                    thi[u] = hh;
                    tlo[u] = f2bf(v - bf2f(hh));
                }
                int byteoff = (c64 * 256 + kb * 2) ^ ((c64 & 7) << 4);
                *(uint4*)((char*)Bt[0] + byteoff) = *(const uint4*)thi;
                *(uint4*)((char*)Bt[1] + byteoff) = *(const uint4*)tlo;
            }
        }
        __syncthreads();   // Bt ready
#pragma unroll
        for (int ks = 0; ks < 4; ++ks) {
            int k0 = ks * 32 + kg * 8;
#pragma unroll
            for (int ct = 0; ct < 4; ++ct) {
                int c64 = ct * 16 + cl;
                int byteoff = (c64 * 256 + k0 * 2) ^ ((c64 & 7) << 4);
                bf16x8 bhi = *(const bf16x8*)((const char*)Bt[0] + byteoff);
                bf16x8 blo = *(const bf16x8*)((const char*)Bt[1] + byteoff);
                int ci = h * 4 + ct;       // global col tile: c = ci*16 + cl
                acc[ci] = __builtin_amdgcn_mfma_f32_16x16x32_bf16(
                    ahi[ks], bhi, acc[ci], 0, 0, 0);
                acc[ci] = __builtin_amdgcn_mfma_f32_16x16x32_bf16(
                    ahi[ks], blo, acc[ci], 0, 0, 0);
                acc[ci] = __builtin_amdgcn_mfma_f32_16x16x32_bf16(
                    alo[ks], bhi, acc[ci], 0, 0, 0);
            }
        }
    }

    // ---- epilogue 1: asv/adv row dots via in-register shuffle reduce ----
    // C/D layout: col = ci*16 + cl, row(within wave tile) = kg*4 + r.
    {
        float ps[4] = {0.f, 0.f, 0.f, 0.f};
        float pd[4] = {0.f, 0.f, 0.f, 0.f};
#pragma unroll
        for (int ci = 0; ci < 8; ++ci) {
            float as_ = a_src[ci * 16 + cl];
            float ad_ = a_dst[ci * 16 + cl];
#pragma unroll
            for (int r = 0; r < 4; ++r) {
                ps[r] += acc[ci][r] * as_;
                pd[r] += acc[ci][r] * ad_;
            }
        }
#pragma unroll
        for (int r = 0; r < 4; ++r) {
#pragma unroll
            for (int off = 1; off < 16; off <<= 1) {
                ps[r] += __shfl_xor(ps[r], off, 64);
                pd[r] += __shfl_xor(pd[r], off, 64);
            }
        }
        if (cl == 0) {
#pragma unroll
            for (int r = 0; r < 4; ++r) {
                int rr = row0 + wv * 16 + kg * 4 + r;
                if (rr < n) { asv[rr] = ps[r]; adv[rr] = pd[r]; }
            }
        }
    }

    // ---- epilogue 2: hb bf16 via LDS transpose (reuse Bt[0] as Cst) ----
    __syncthreads();   // all waves done reading Bt
    unsigned short* Cst = Bt[0];       // [64][128] ushort = 16KB
#pragma unroll
    for (int ci = 0; ci < 8; ++ci) {
#pragma unroll
        for (int r = 0; r < 4; ++r)
            Cst[(wv * 16 + kg * 4 + r) * 128 + ci * 16 + cl] = f2bf(acc[ci][r]);
    }
    __syncthreads();
    {
        int r = tid >> 2, cb = (tid & 3) * 32;   // 64B per thread
        int grow = row0 + r;
        if (grow < n) {
            uint4* dst = (uint4*)(Cb + (size_t)grow * 128 + cb);
            const uint4* src = (const uint4*)(Cst + r * 128 + cb);
            dst[0] = src[0]; dst[1] = src[1]; dst[2] = src[2]; dst[3] = src[3];
        }
    }
}

// Phase B: one block per bin (512 dsts). LDS-rank the bin's edges into col
// slots; write cnt[d] for every dst in range (zeros included).
__global__ __launch_bounds__(512) void binbuild(const unsigned* __restrict__ binBuf,
                                                const int* __restrict__ binCnt,
                                                unsigned short* __restrict__ col,
                                                int* __restrict__ cnt, int n) {
    __shared__ int lc[512];
    const int b = blockIdx.x;
    const int lo = b << 9;
    const int tid = threadIdx.x;
    lc[tid] = 0;
    __syncthreads();
    int m = binCnt[b];
    if (m > CAPB) m = CAPB;
    for (int i = tid; i < m; i += 512) {
        unsigned u = binBuf[(size_t)b * CAPB + i];
        int d = (int)(u >> 16);
        int s = (int)(u & 0xFFFFu);
        int p = atomicAdd(&lc[d - lo], 1);
        if (p < CAP) col[(size_t)d * CAP + p] = (unsigned short)s;
    }
    __syncthreads();
    int d = lo + tid;
    if (d < n) cnt[d] = lc[tid];
}

// one wave per dst node: segment softmax + weighted feature sum.
// Phase A fp32 (asv/adv); virtual self-loop at entry deg (c=w).
// Phase B gathers bf16 rows from hb (8B/lane, half-wave layout), fp32 acc.
// (R19-proven form; cnt now stride-1)
__global__ __launch_bounds__(256) void aggregate(const unsigned short* __restrict__ hb,
                                                 const int* __restrict__ cnt,
                                                 const unsigned short* __restrict__ col,
                                                 const float* __restrict__ asv,
                                                 const float* __restrict__ adv,
                                                 const float* __restrict__ bias,
                                                 float* __restrict__ out, int n) {
    __shared__ int   scol[4][128];
    __shared__ float swt[4][128];
    const int wv = threadIdx.x >> 6;
    const int lane = threadIdx.x & 63;
    const int w = blockIdx.x * 4 + wv;
    if (w >= n) return;
    int deg = cnt[w];
    if (deg > CAP - 1) deg = CAP - 1;   // keep D <= 128 (statistically impossible)
    const int D = deg + 1;              // + virtual self-loop at entry deg
    const size_t start = (size_t)w * CAP;
    const float ad = adv[w];

    // ---- phase A: logits, wave max, exp-sum; stash (col, wgt) in LDS ----
    int c0 = 0, c1 = 0;
    float l0 = -INFINITY, l1 = -INFINITY;
    if (lane < D) {
        c0 = (lane < deg) ? (int)col[start + lane] : w;
        l0 = asv[c0] + ad;
        l0 = l0 > 0.f ? l0 : LEAKY * l0;
    }
    if (64 + lane < D) {
        c1 = (64 + lane < deg) ? (int)col[start + 64 + lane] : w;
        l1 = asv[c1] + ad;
        l1 = l1 > 0.f ? l1 : LEAKY * l1;
    }
    float m = fmaxf(l0, l1);
#pragma unroll
    for (int off = 32; off; off >>= 1) m = fmaxf(m, __shfl_xor(m, off, 64));
    float e0 = (lane < D) ? __expf(l0 - m) : 0.f;
    float e1 = (64 + lane < D) ? __expf(l1 - m) : 0.f;
    float s = e0 + e1;
#pragma unroll
    for (int off = 32; off; off >>= 1) s += __shfl_xor(s, off, 64);
    float inv = 1.f / s;
    if (lane < D)      { scol[wv][lane] = c0;      swt[wv][lane] = e0; }
    if (64 + lane < D) { scol[wv][64 + lane] = c1; swt[wv][64 + lane] = e1; }
    // wave-synchronous LDS producer/consumer: no barrier needed

    // ---- phase B: half-wave bf16 rows (8B/lane), 16 entries per iter ----
    const int hw = lane >> 5;        // half-wave 0/1
    const int sl = lane & 31;        // sub-lane: feature group [4sl..4sl+4)
    float4 aa[8];
#pragma unroll
    for (int j = 0; j < 8; ++j) aa[j] = make_float4(0.f, 0.f, 0.f, 0.f);
    for (int i = 0; i < D; i += 16) {
        int cs[8]; float ws[8];
#pragma unroll
        for (int j = 0; j < 8; ++j) {
            int idx = i + 2 * j + hw;
            int cl = idx < D ? idx : D - 1;       // clamp: load valid row
            cs[j] = scol[wv][cl];
            ws[j] = (idx < D) ? swt[wv][idx] : 0.f;   // mask via zero wgt
        }
        ushort4 rs[8];
#pragma unroll
        for (int j = 0; j < 8; ++j)
            rs[j] = *((const ushort4*)(hb + (size_t)cs[j] * 128) + sl);
#pragma unroll
        for (int j = 0; j < 8; ++j) {
            aa[j].x += ws[j] * bf2f(rs[j].x);
            aa[j].y += ws[j] * bf2f(rs[j].y);
            aa[j].z += ws[j] * bf2f(rs[j].z);
            aa[j].w += ws[j] * bf2f(rs[j].w);
        }
    }
#pragma unroll
    for (int j = 1; j < 8; ++j) {
        aa[0].x += aa[j].x; aa[0].y += aa[j].y;
        aa[0].z += aa[j].z; aa[0].w += aa[j].w;
    }
    // cross-half combine: lane and lane^32 hold same feature group
    aa[0].x += __shfl_xor(aa[0].x, 32);
    aa[0].y += __shfl_xor(aa[0].y, 32);
    aa[0].z += __shfl_xor(aa[0].z, 32);
    aa[0].w += __shfl_xor(aa[0].w, 32);
    if (hw == 0) {
        float4 b = ((const float4*)bias)[sl];
        float4 o;
        o.x = fmaxf(aa[0].x * inv + b.x, 0.f);
        o.y = fmaxf(aa[0].y * inv + b.y, 0.f);
        o.z = fmaxf(aa[0].z * inv + b.z, 0.f);
        o.w = fmaxf(aa[0].w * inv + b.w, 0.f);
        *((float4*)(out + (size_t)w * 128) + sl) = o;
    }
}

// one block (128 threads) per graph: max/mean pool + fc dot. Graph node range
// by binary search on sorted batch (R13-proven).
__global__ __launch_bounds__(128) void poolfc(const float* __restrict__ h2,
                                              const int* __restrict__ batch,
                                              const float* __restrict__ fcw,
                                              const float* __restrict__ fcb,
                                              float* __restrict__ out, int G, int n) {
    __shared__ int seg[2];
    int g = blockIdx.x;
    int f = threadIdx.x;
    if (f < 2) {
        int target = g + f;          // first idx with batch[idx] >= target
        int lo = 0, hi = n;
        while (lo < hi) {
            int mid = (lo + hi) >> 1;
            if (batch[mid] < target) lo = mid + 1; else hi = mid;
        }
        seg[f] = lo;
    }
    __syncthreads();
    int s = seg[0], e = seg[1];
    float m = -INFINITY, sum = 0.f;
    for (int node = s; node < e; ++node) {
        float v = h2[(size_t)node * 128 + f];
        m = fmaxf(m, v);
        sum += v;
    }
    int cnt = e - s;
    float maxp = (cnt > 0) ? m : 0.f;
    float cden = (float)(cnt > 0 ? cnt : 1);
    float meanp = sum / cden;
    float p = maxp * fcw[f] + meanp * fcw[128 + f];
    __shared__ float red[128];
    red[f] = p;
    __syncthreads();
    for (int off = 64; off; off >>= 1) {
        if (f < off) red[f] += red[f + off];
        __syncthreads();
    }
    if (f == 0) out[g] = red[0] + fcb[0];
}

extern "C" void kernel_launch(void* const* d_in, const int* in_sizes, int n_in,
                              void* d_out, int out_size, void* d_ws, size_t ws_size,
                              hipStream_t stream) {
    const int N = in_sizes[0] / 128;
    const int E = in_sizes[1] / 2;
    const int G = out_size;

    const float* x      = (const float*)d_in[0];
    const int*   ei     = (const int*)d_in[1];
    const int*   batch  = (const int*)d_in[2];
    const float* W1     = (const float*)d_in[3];
    const float* a_src1 = (const float*)d_in[4];
    const float* a_dst1 = (const float*)d_in[5];
    const float* b1     = (const float*)d_in[6];
    const float* W2     = (const float*)d_in[7];
    const float* a_src2 = (const float*)d_in[8];
    const float* a_dst2 = (const float*)d_in[9];
    const float* b2     = (const float*)d_in[10];
    const float* fcw    = (const float*)d_in[11];
    const float* fcb    = (const float*)d_in[12];
    float* out = (float*)d_out;

    const int NBINS = (N + 511) >> 9;    // 98 for N=50000 (<=128 assumed)

    // workspace carve (256B aligned).
    char* wp = (char*)d_ws;
    auto alloc = [&](size_t bytes) -> void* {
        void* p = (void*)wp;
        wp += (bytes + 255) & ~(size_t)255;
        return p;
    };
    int* cnt        = (int*)alloc(sizeof(int) * N);
    int* binCnt     = (int*)alloc(sizeof(int) * 128);
    unsigned* binBuf = (unsigned*)alloc(sizeof(unsigned) * (size_t)NBINS * CAPB);
    unsigned short* col = (unsigned short*)alloc(sizeof(unsigned short) * (size_t)N * CAP);
    float* ha    = (float*)alloc(sizeof(float) * (size_t)N * 128);
    unsigned short* hb = (unsigned short*)alloc(sizeof(unsigned short) * (size_t)N * 128);
    float* asv   = (float*)alloc(sizeof(float) * N);
    float* adv   = (float*)alloc(sizeof(float) * N);

    hipMemsetAsync(binCnt, 0, sizeof(int) * 128, stream);

    const int gemmGrid = (N + 63) / 64;
    const int waveGrid = (N + 3) / 4;      // 4 waves per 256-thread block
    const int binGrid  = (E + 4095) / 4096;

    // layer 1 (input = relu(x)) fused with phase-A edge binning.
    gemmscat<<<gemmGrid + binGrid, 256, 0, stream>>>(
        x, W1, hb, a_src1, a_dst1, asv, adv, N, 1, gemmGrid, ei,
        binCnt, binBuf, E);
    // phase B: build col/cnt from bins
    binbuild<<<NBINS, 512, 0, stream>>>(binBuf, binCnt, col, cnt, N);
    aggregate<<<waveGrid, 256, 0, stream>>>(hb, cnt, col, asv, adv, b1, ha, N);

    // layer 2: fp32 ha input; no binning blocks.
    gemmscat<<<gemmGrid, 256, 0, stream>>>(
        ha, W2, hb, a_src2, a_dst2, asv, adv, N, 0, gemmGrid, ei,
        binCnt, binBuf, E);
    aggregate<<<waveGrid, 256, 0, stream>>>(hb, cnt, col, asv, adv, b2, ha, N);

    // pooling + fc
    poolfc<<<G, 128, 0, stream>>>(ha, batch, fcw, fcb, out, G, N);
}